// Round 4
// baseline (249.445 us; speedup 1.0000x reference)
//
#include <hip/hip_runtime.h>

#define ROW_LEN 2048
#define BLOCK   256
#define EPS     1e-5f

typedef float floatx4 __attribute__((ext_vector_type(4)));

// Per-row sum of squares. Device BSS: no hipMalloc, graph-capture safe.
__device__ float g_rowsum[32768];

// ---------------- Pass 0: zero the row sums (graph-safe, no runtime API) ----
__global__ __launch_bounds__(BLOCK) void RMSNorm_zero_kernel(int rows)
{
    const int i = blockIdx.x * BLOCK + threadIdx.x;
    if (i < rows) g_rowsum[i] = 0.f;
}

// ---------------- Pass 1: streaming reduce -------------------------------
// Grid-stride, long-lived blocks — the loop shape that runs at ~6.5 TB/s in
// this harness (fill / pass2 evidence), instead of the wave-per-row
// burst-8-then-drain shape that caps at ~2.5 TB/s.
// A wave's 64 lanes cover 64 consecutive float4 = 256 floats, aligned, so the
// whole wave sits in ONE row (512 float4/row) -> one atomicAdd per wave/iter.
__global__ __launch_bounds__(BLOCK) void RMSNorm_pass1_kernel(
    const float* __restrict__ x, int n4)
{
    const floatx4* __restrict__ x4 = reinterpret_cast<const floatx4*>(x);
    const int lane   = threadIdx.x & 63;
    const int stride = gridDim.x * BLOCK;

    int i = blockIdx.x * BLOCK + threadIdx.x;
    floatx4 cur = x4[i];                       // prologue load

    #pragma unroll 1
    for (int it = 0; it < 8; ++it) {
        const int inext = i + stride;
        floatx4 nxt = cur;
        if (it < 7) nxt = x4[inext];           // prefetch next iteration

        float s = cur.x * cur.x + cur.y * cur.y + cur.z * cur.z + cur.w * cur.w;
        #pragma unroll
        for (int off = 32; off > 0; off >>= 1)
            s += __shfl_xor(s, off, 64);

        if (lane == 0)
            atomicAdd(&g_rowsum[i >> 9], s);   // 8 contributions per row

        i = inext;
        cur = nxt;
    }
}

// ---------------- Pass 2: streaming scale --------------------------------
// out[i] = x[i] * rsqrt(rowsum/2048+eps) * g[col]. x is L3-hot from pass 1;
// nt stores keep `out` from evicting x mid-pass.
__global__ __launch_bounds__(BLOCK) void RMSNorm_pass2_kernel(
    const float* __restrict__ x, const float* __restrict__ g,
    float* __restrict__ out, int n4)
{
    const floatx4* __restrict__ x4 = reinterpret_cast<const floatx4*>(x);
    const floatx4* __restrict__ g4 = reinterpret_cast<const floatx4*>(g);
    floatx4* __restrict__       o4 = reinterpret_cast<floatx4*>(out);

    const int stride = gridDim.x * BLOCK;
    for (int i = blockIdx.x * BLOCK + threadIdx.x; i < n4; i += stride) {
        const floatx4 xv = x4[i];
        const float   sc = rsqrtf(g_rowsum[i >> 9] * (1.0f / (float)ROW_LEN) + EPS);
        const floatx4 gv = g4[i & 511];
        __builtin_nontemporal_store(xv * sc * gv, &o4[i]);
    }
}

extern "C" void kernel_launch(void* const* d_in, const int* in_sizes, int n_in,
                              void* d_out, int out_size, void* d_ws, size_t ws_size,
                              hipStream_t stream) {
    const float* x = (const float*)d_in[0];
    const float* g = (const float*)d_in[1];
    float* out = (float*)d_out;

    const int rows = in_sizes[0] / ROW_LEN;   // 16384
    const int n4   = rows * (ROW_LEN / 4);    // 8388608 float4

    RMSNorm_zero_kernel<<<(rows + BLOCK - 1) / BLOCK, BLOCK, 0, stream>>>(rows);
    RMSNorm_pass1_kernel<<<4096, BLOCK, 0, stream>>>(x, n4);
    RMSNorm_pass2_kernel<<<4096, BLOCK, 0, stream>>>(x, g, out, n4);
}

// Round 5
// 236.176 us; speedup vs baseline: 1.0562x; 1.0562x over previous
//
#include <hip/hip_runtime.h>

#define ROW_LEN 2048
#define R4      (ROW_LEN / 4)      // 512 float4 per row
#define BLOCK   512                 // 8 waves: 4 producer + 4 consumer
#define ROWS_PER_BLOCK 8
#define EPS     1e-5f

// Producer/consumer wave-specialized RMSNorm.
// Producer waves (0-3): pure read stream from HBM + per-row butterfly reduce,
//   depositing rows + partial sums into a double-buffered LDS pipeline.
// Consumer waves (4-7): pure write stream — pull row from LDS, scale, store.
// Read and write memory streams run CONCURRENTLY at full depth; no wave ever
// alternates direction, no vmcnt-drain-then-reduce on the read path.
__global__ __launch_bounds__(BLOCK) void RMSNorm_56607668961691_kernel(
    const float* __restrict__ x,
    const float* __restrict__ g,
    float* __restrict__ out)
{
    __shared__ float4 buf[2][R4];      // 2 x 8 KB row buffers
    __shared__ float  psum[2][4];      // per-producer-wave partial sums

    const int tid  = threadIdx.x;
    const int w    = tid >> 6;               // wave id 0..7
    const int lane = tid & 63;
    const bool producer = (w < 4);           // wave-uniform: no divergence
    const int pw   = producer ? w : (w - 4); // role-local wave id 0..3
    const int c    = pw * 64 + lane;         // chunk id 0..255

    const size_t row0 = (size_t)blockIdx.x * ROWS_PER_BLOCK;
    const float4* __restrict__ x4 = reinterpret_cast<const float4*>(x) + row0 * R4;
    float4* __restrict__       o4 = reinterpret_cast<float4*>(out)     + row0 * R4;
    const float4* __restrict__ g4 = reinterpret_cast<const float4*>(g);

    // Consumers keep their g slice in registers (g is 8 KB, read once).
    float4 ga, gb;
    if (!producer) { ga = g4[c]; gb = g4[c + 256]; }

    // Row pipeline: stage t produces row t and consumes row t-1.
    // One barrier per stage; double buffer means producer writes buf[t&1]
    // while consumer reads buf[(t-1)&1] — never the same buffer.
    for (int t = 0; t <= ROWS_PER_BLOCK; ++t) {
        const int b = t & 1;
        if (producer) {
            if (t < ROWS_PER_BLOCK) {
                const float4 v0 = x4[(size_t)t * R4 + c];
                const float4 v1 = x4[(size_t)t * R4 + c + 256];
                buf[b][c]       = v0;
                buf[b][c + 256] = v1;
                float s = v0.x * v0.x + v0.y * v0.y + v0.z * v0.z + v0.w * v0.w
                        + v1.x * v1.x + v1.y * v1.y + v1.z * v1.z + v1.w * v1.w;
                #pragma unroll
                for (int off = 32; off > 0; off >>= 1)
                    s += __shfl_xor(s, off, 64);
                if (lane == 0) psum[b][pw] = s;
            }
        } else {
            if (t > 0) {
                const int bb = b ^ 1;
                const int tr = t - 1;
                const float total = psum[bb][0] + psum[bb][1]
                                  + psum[bb][2] + psum[bb][3];
                const float scale = rsqrtf(total * (1.0f / (float)ROW_LEN) + EPS);
                const float4 v0 = buf[bb][c];
                const float4 v1 = buf[bb][c + 256];
                float4 o0, o1;
                o0.x = v0.x * scale * ga.x;  o0.y = v0.y * scale * ga.y;
                o0.z = v0.z * scale * ga.z;  o0.w = v0.w * scale * ga.w;
                o1.x = v1.x * scale * gb.x;  o1.y = v1.y * scale * gb.y;
                o1.z = v1.z * scale * gb.z;  o1.w = v1.w * scale * gb.w;
                o4[(size_t)tr * R4 + c]       = o0;
                o4[(size_t)tr * R4 + c + 256] = o1;
            }
        }
        __syncthreads();
    }
}

extern "C" void kernel_launch(void* const* d_in, const int* in_sizes, int n_in,
                              void* d_out, int out_size, void* d_ws, size_t ws_size,
                              hipStream_t stream) {
    const float* x = (const float*)d_in[0];
    const float* g = (const float*)d_in[1];
    float* out = (float*)d_out;

    const int rows = in_sizes[0] / ROW_LEN;        // 16384
    const int grid = rows / ROWS_PER_BLOCK;        // 2048 blocks, 4/CU, 32 waves/CU
    RMSNorm_56607668961691_kernel<<<grid, BLOCK, 0, stream>>>(x, g, out);
}

// Round 6
// 230.655 us; speedup vs baseline: 1.0815x; 1.0239x over previous
//
#include <hip/hip_runtime.h>

#define ROW_LEN 2048
#define BLOCK   256
#define EPS     1e-5f

// Wave-per-row RMSNorm with FORCED 16-deep load burst.
//
// Key evidence from rounds 1-5: every structure ran at ~81 us with <=2 reads
// in flight per lane (VGPR_Count 20-60 proves the compiler shrank the burst).
// sched_barrier(0) pins all 16 loads (8x x, 8x g) BEFORE any consumer, so
// they issue back-to-back and their latencies overlap.
__global__ __launch_bounds__(BLOCK) void RMSNorm_56607668961691_kernel(
    const float* __restrict__ x,
    const float* __restrict__ g,
    float* __restrict__ out)
{
    const int wave = threadIdx.x >> 6;
    const int lane = threadIdx.x & 63;
    const size_t row = (size_t)blockIdx.x * (BLOCK / 64) + wave;

    const float4* __restrict__ xr   = reinterpret_cast<const float4*>(x + row * ROW_LEN) + lane;
    float4* __restrict__       outr = reinterpret_cast<float4*>(out + row * ROW_LEN) + lane;
    const float4* __restrict__ gv   = reinterpret_cast<const float4*>(g) + lane;

    // 2048 floats = 512 float4 = 64 lanes x 8 float4, coalesced 1 KiB/wave/instr.
    float4 v[8];
    float4 gr[8];
    #pragma unroll
    for (int j = 0; j < 8; ++j) v[j]  = xr[j * 64];   // 8 HBM loads
    #pragma unroll
    for (int j = 0; j < 8; ++j) gr[j] = gv[j * 64];   // 8 L2-hit loads (g = 8 KB)

    // Nothing below may be hoisted above this point: all 16 loads are ISSUED
    // (outstanding) before the first FMA. This is the whole experiment.
    __builtin_amdgcn_sched_barrier(0);

    // 4 independent accumulator chains; compiler waits per-use (vmcnt(N)),
    // consuming v[0] while v[1..7] are still in flight.
    float s0 = 0.f, s1 = 0.f, s2 = 0.f, s3 = 0.f;
    #pragma unroll
    for (int j = 0; j < 8; ++j) {
        s0 += v[j].x * v[j].x;
        s1 += v[j].y * v[j].y;
        s2 += v[j].z * v[j].z;
        s3 += v[j].w * v[j].w;
    }
    float ss = (s0 + s1) + (s2 + s3);

    // 64-lane butterfly; every lane ends with the row total. No LDS, no barrier.
    #pragma unroll
    for (int off = 32; off > 0; off >>= 1)
        ss += __shfl_xor(ss, off, 64);

    const float scale = rsqrtf(ss * (1.0f / (float)ROW_LEN) + EPS);

    // Pure-store tail: g already in registers, stores are fire-and-forget.
    #pragma unroll
    for (int j = 0; j < 8; ++j) {
        float4 o;
        o.x = v[j].x * scale * gr[j].x;
        o.y = v[j].y * scale * gr[j].y;
        o.z = v[j].z * scale * gr[j].z;
        o.w = v[j].w * scale * gr[j].w;
        outr[j * 64] = o;
    }
}

extern "C" void kernel_launch(void* const* d_in, const int* in_sizes, int n_in,
                              void* d_out, int out_size, void* d_ws, size_t ws_size,
                              hipStream_t stream) {
    const float* x = (const float*)d_in[0];
    const float* g = (const float*)d_in[1];
    float* out = (float*)d_out;

    const int rows = in_sizes[0] / ROW_LEN;          // 16384
    const int grid = rows / (BLOCK / 64);            // 4096 blocks
    RMSNorm_56607668961691_kernel<<<grid, BLOCK, 0, stream>>>(x, g, out);
}